// Round 1
// baseline (337.115 us; speedup 1.0000x reference)
//
#include <hip/hip_runtime.h>
#include <math.h>

#define BB  2
#define SS  2048
#define HID 2048
#define NH  16
#define HD  128
#define MT  (BB * SS)      // 4096 total rows
#define NC  (HID + 2 * HD) // 2304 fused QKV output cols
#define QK_SCALE 0.08838834764831845f  // 1/sqrt(128)

typedef unsigned short ushort_t;
typedef unsigned int uint_t;
typedef __bf16 bf16x8 __attribute__((ext_vector_type(8)));
typedef short short8 __attribute__((ext_vector_type(8)));
typedef float f32x4 __attribute__((ext_vector_type(4)));

// round-to-nearest-even (used in one-time weight/activation converts)
__device__ __forceinline__ ushort_t f2bf(float x) {
    union { float f; uint_t u; } a; a.f = x;
    return (ushort_t)((a.u + 0x7FFFu + ((a.u >> 16) & 1u)) >> 16);
}
// 2-instr round-half-up — hot paths (≈RNE for continuous data)
__device__ __forceinline__ ushort_t f2bf_fast(float x) {
    union { float f; uint_t u; } a; a.f = x;
    return (ushort_t)((a.u + 0x8000u) >> 16);
}

// Swizzled LDS layout for one 128x32 bf16 tile (8 KB): logical (row r, 16B
// chunk c) -> 128B physical rows, slot ^= row'&7. All ds_read_b128 frag reads
// land 2-way per bank (free); staging computes the inverse in GLOBAL addrs.
__device__ __forceinline__ int sw_addr(int r, int c) {
    return ((r >> 1) << 6) + ((((((r & 1) << 2) | c)) ^ ((r >> 1) & 7)) << 3);
}

// compiler memory fence (no instruction) — keeps LDS/global ops from being
// hoisted/sunk across raw s_barrier (rule: barrier builtin is not an IR fence)
#define CFENCE() asm volatile("" ::: "memory")

// ---------------------------------------------------------------------------
// fp32 -> bf16 elementwise (hs conversion), 8 elems/thread.
// ---------------------------------------------------------------------------
__global__ __launch_bounds__(256) void conv_bf16_kernel(
    const float* __restrict__ in, ushort_t* __restrict__ outb)
{
    const size_t i = ((size_t)blockIdx.x * 256 + threadIdx.x) * 8;
    const float4 a = *(const float4*)&in[i];
    const float4 b = *(const float4*)&in[i + 4];
    short8 o;
    o[0] = (short)f2bf(a.x); o[1] = (short)f2bf(a.y);
    o[2] = (short)f2bf(a.z); o[3] = (short)f2bf(a.w);
    o[4] = (short)f2bf(b.x); o[5] = (short)f2bf(b.y);
    o[6] = (short)f2bf(b.z); o[7] = (short)f2bf(b.w);
    *(short8*)&outb[i] = o;
}

// ---------------------------------------------------------------------------
// W[K][N] fp32 -> WT[N][K] bf16 (transpose), 64x64 tiles.
// ---------------------------------------------------------------------------
__global__ __launch_bounds__(256) void convT_kernel(
    const float* __restrict__ W, ushort_t* __restrict__ Th, int K, int N)
{
    __shared__ float Ts[64][65];
    const int t = threadIdx.x;
    const int k0 = blockIdx.x * 64, n0 = blockIdx.y * 64;
    const int rr = t >> 4, c4 = (t & 15) * 4;
#pragma unroll
    for (int i = 0; i < 4; i++) {
        const int k = rr + i * 16;
        const float4 v = *(const float4*)&W[(size_t)(k0 + k) * N + n0 + c4];
        Ts[k][c4 + 0] = v.x; Ts[k][c4 + 1] = v.y;
        Ts[k][c4 + 2] = v.z; Ts[k][c4 + 3] = v.w;
    }
    __syncthreads();
    const int n = t >> 2, kc = (t & 3) * 16;
    short8 hv[2];
#pragma unroll
    for (int jj = 0; jj < 16; jj++)
        hv[jj >> 3][jj & 7] = (short)f2bf(Ts[kc + jj][n]);
    const size_t ob = (size_t)(n0 + n) * K + k0 + kc;
    *(short8*)&Th[ob]     = hv[0];
    *(short8*)&Th[ob + 8] = hv[1];
}

// ---------------------------------------------------------------------------
// Fused QKV projection, plain bf16 single-product (m97 shape).
// A bf16 [M][K]; WT bf16 [NC][K]. Epilogue per 128-col tile: q/k/vT.
// ---------------------------------------------------------------------------
__global__ __launch_bounds__(256, 2) void gemm_qkv_kernel(
    const ushort_t* __restrict__ Ab, const ushort_t* __restrict__ WT,
    const float* __restrict__ bq, const float* __restrict__ bk,
    const float* __restrict__ bv,
    ushort_t* __restrict__ qb, ushort_t* __restrict__ kb,
    ushort_t* __restrict__ vtb)
{
    __shared__ short lds[8192];   // AH | BH (4096 shorts / 8 KB each)
    constexpr int AH = 0, BH = 4096;
    constexpr int K = HID;
    const int t  = threadIdx.x;
    const int wv = t >> 6, ln = t & 63;
    const int row0 = blockIdx.y * 128, col0 = blockIdx.x * 128;

    size_t agbase[2], bgbase[2];
    int    lbase[2];
#pragma unroll
    for (int i = 0; i < 2; i++) {
        const int I = wv * 2 + i;
        const int lrow = I * 8 + (ln >> 3);
        const int sb = (ln & 7) ^ (lrow & 7);
        const int rr = lrow * 2 + (sb >> 2);
        const int cc = sb & 3;
        agbase[i] = (size_t)(row0 + rr) * K + cc * 8;
        bgbase[i] = (size_t)(col0 + rr) * K + cc * 8;
        lbase[i] = I * 512;
    }

    const int wm0 = (wv & 1) * 64, wn0 = (wv >> 1) * 64;
    const int q = ln >> 4, lm = ln & 15;
    int aoff[4], boff[4];
#pragma unroll
    for (int i = 0; i < 4; i++) aoff[i] = sw_addr(wm0 + i * 16 + lm, q);
#pragma unroll
    for (int j = 0; j < 4; j++) boff[j] = sw_addr(wn0 + j * 16 + lm, q);

    f32x4 acc[4][4];
#pragma unroll
    for (int i = 0; i < 4; i++)
#pragma unroll
        for (int j = 0; j < 4; j++) acc[i][j] = 0.f;

    for (int k0 = 0; k0 < K; k0 += 32) {
        __syncthreads();
#pragma unroll
        for (int i = 0; i < 2; i++) {
            __builtin_amdgcn_global_load_lds(
                (const __attribute__((address_space(1))) void*)(Ab + agbase[i] + k0),
                (__attribute__((address_space(3))) void*)&lds[AH + lbase[i]], 16, 0, 0);
            __builtin_amdgcn_global_load_lds(
                (const __attribute__((address_space(1))) void*)(WT + bgbase[i] + k0),
                (__attribute__((address_space(3))) void*)&lds[BH + lbase[i]], 16, 0, 0);
        }
        __syncthreads();

        bf16x8 ah[4], bh[4];
#pragma unroll
        for (int i = 0; i < 4; i++) ah[i] = *(const bf16x8*)&lds[AH + aoff[i]];
#pragma unroll
        for (int j = 0; j < 4; j++) bh[j] = *(const bf16x8*)&lds[BH + boff[j]];
#pragma unroll
        for (int i = 0; i < 4; i++)
#pragma unroll
            for (int j = 0; j < 4; j++)
                acc[i][j] = __builtin_amdgcn_mfma_f32_16x16x32_bf16(ah[i], bh[j], acc[i][j], 0, 0, 0);
    }

    // epilogue: tile is entirely q (col0<2048), k (col0==2048) or v (col0==2176)
    const int mode = (col0 < HID) ? 0 : ((col0 == HID) ? 1 : 2);
    const float* bsel = (mode == 0) ? bq : ((mode == 1) ? bk : bv);
    const int noff = (mode == 0) ? 0 : ((mode == 1) ? HID : HID + HD);
    float bj[4];
#pragma unroll
    for (int j = 0; j < 4; j++) bj[j] = bsel[col0 - noff + wn0 + j * 16 + lm];
#pragma unroll
    for (int i = 0; i < 4; i++) {
        const int mb = row0 + wm0 + i * 16 + q * 4;
#pragma unroll
        for (int j = 0; j < 4; j++) {
            const int nn = col0 + wn0 + j * 16 + lm;
#pragma unroll
            for (int rr2 = 0; rr2 < 4; rr2++) {
                const float v = acc[i][j][rr2] + bj[j];
                if (mode == 0)      qb [(size_t)(mb + rr2) * HID + nn]           = f2bf_fast(v * QK_SCALE);
                else if (mode == 1) kb [(size_t)(mb + rr2) * HD + (nn - HID)]    = f2bf_fast(v);
                else                vtb[(size_t)(nn - HID - HD) * MT + mb + rr2] = f2bf_fast(v);
            }
        }
    }
}

// ---------------------------------------------------------------------------
// O-projection, plain bf16 single-product. A bf16 [M][K]; WT bf16 [N][K].
// Output fp32 + bias.
// ---------------------------------------------------------------------------
__global__ __launch_bounds__(256, 2) void gemm_oproj_kernel(
    const ushort_t* __restrict__ Ab, const ushort_t* __restrict__ WT,
    const float* __restrict__ bias, float* __restrict__ C, int M, int N, int K)
{
    __shared__ short lds[8192];
    constexpr int AH = 0, BH = 4096;
    const int t  = threadIdx.x;
    const int wv = t >> 6, ln = t & 63;
    const int row0 = blockIdx.y * 128, col0 = blockIdx.x * 128;

    size_t agbase[2], bgbase[2];
    int    lbase[2];
#pragma unroll
    for (int i = 0; i < 2; i++) {
        const int I = wv * 2 + i;
        const int lrow = I * 8 + (ln >> 3);
        const int sb = (ln & 7) ^ (lrow & 7);
        const int rr = lrow * 2 + (sb >> 2);
        const int cc = sb & 3;
        agbase[i] = (size_t)(row0 + rr) * K + cc * 8;
        bgbase[i] = (size_t)(col0 + rr) * K + cc * 8;
        lbase[i] = I * 512;
    }

    const int wm0 = (wv & 1) * 64, wn0 = (wv >> 1) * 64;
    const int q = ln >> 4, lm = ln & 15;
    int aoff[4], boff[4];
#pragma unroll
    for (int i = 0; i < 4; i++) aoff[i] = sw_addr(wm0 + i * 16 + lm, q);
#pragma unroll
    for (int j = 0; j < 4; j++) boff[j] = sw_addr(wn0 + j * 16 + lm, q);

    f32x4 acc[4][4];
#pragma unroll
    for (int i = 0; i < 4; i++)
#pragma unroll
        for (int j = 0; j < 4; j++) acc[i][j] = 0.f;

    for (int k0 = 0; k0 < K; k0 += 32) {
        __syncthreads();
#pragma unroll
        for (int i = 0; i < 2; i++) {
            __builtin_amdgcn_global_load_lds(
                (const __attribute__((address_space(1))) void*)(Ab + agbase[i] + k0),
                (__attribute__((address_space(3))) void*)&lds[AH + lbase[i]], 16, 0, 0);
            __builtin_amdgcn_global_load_lds(
                (const __attribute__((address_space(1))) void*)(WT + bgbase[i] + k0),
                (__attribute__((address_space(3))) void*)&lds[BH + lbase[i]], 16, 0, 0);
        }
        __syncthreads();

        bf16x8 ah[4], bh[4];
#pragma unroll
        for (int i = 0; i < 4; i++) ah[i] = *(const bf16x8*)&lds[AH + aoff[i]];
#pragma unroll
        for (int j = 0; j < 4; j++) bh[j] = *(const bf16x8*)&lds[BH + boff[j]];
#pragma unroll
        for (int i = 0; i < 4; i++)
#pragma unroll
            for (int j = 0; j < 4; j++)
                acc[i][j] = __builtin_amdgcn_mfma_f32_16x16x32_bf16(ah[i], bh[j], acc[i][j], 0, 0, 0);
    }

    float bj[4];
#pragma unroll
    for (int j = 0; j < 4; j++) bj[j] = bias[col0 + wn0 + j * 16 + lm];
#pragma unroll
    for (int i = 0; i < 4; i++) {
        const int mb = row0 + wm0 + i * 16 + q * 4;
#pragma unroll
        for (int j = 0; j < 4; j++) {
            const int nn = col0 + wn0 + j * 16 + lm;
#pragma unroll
            for (int rr2 = 0; rr2 < 4; rr2++)
                C[(size_t)(mb + rr2) * N + nn] = acc[i][j][rr2] + bj[j];
        }
    }
}

// ---------------------------------------------------------------------------
// MFMA flash attention (MQA), bf16/fp32, no online max (scores bounded).
// v2: K/V tiles DOUBLE-BUFFERED in LDS, next tile issued before computing the
// current one, counted s_waitcnt vmcnt(8) + raw s_barrier (never a vmcnt(0)
// drain in the main loop) — T3/T4 pipeline; T5 setprio around MFMA clusters.
// LDS = Ks 2x16K + Vts 2x16K + Ps 8K = 72 KB -> 2 blocks/CU.
// Ps is wave-private (each wave writes/reads only its own 16 rows): no
// barrier needed between softmax write and PV read.
// Output plain bf16, aliases qg block-safely (Q consumed before O written).
// ---------------------------------------------------------------------------
__global__ __launch_bounds__(256, 2) void attn_mfma_kernel(
    const ushort_t* __restrict__ qg, const ushort_t* __restrict__ kg,
    const ushort_t* __restrict__ vtg, ushort_t* Oh)
{
    __shared__ short Ks[2][8192], Vts[2][8192], Ps[4096];
    const int b = blockIdx.z, h = blockIdx.y, qt = blockIdx.x;
    const int t = threadIdx.x, wv = t >> 6, ln = t & 63;
    const int q = ln >> 4, lm = ln & 15;
    const int w16 = wv * 16;
    const int am = w16 + lm, amx = am & 15, amx7 = am & 7;

    // --- stage Q through Ks[0], pull A-frags to registers ---
#pragma unroll
    for (int i = 0; i < 4; i++) {
        const int I = wv * 4 + i;
        const int r = 4 * I + (ln >> 4);
        const int c = (ln & 15) ^ (r & 15);
        const ushort_t* src = qg + (size_t)(b * SS + qt * 64 + r) * HID + h * HD + c * 8;
        __builtin_amdgcn_global_load_lds((const __attribute__((address_space(1))) void*)src,
            (__attribute__((address_space(3))) void*)&Ks[0][I * 512], 16, 0, 0);
    }
    __syncthreads();
    bf16x8 aq[4];
#pragma unroll
    for (int ks = 0; ks < 4; ks++)
        aq[ks] = *(const bf16x8*)&Ks[0][am * 128 + (((ks << 2) | q) ^ amx) * 8];
    __syncthreads();   // all waves hold their Q frags before tile-0 K staging

    size_t kbase[4], vbase[4];
#pragma unroll
    for (int i = 0; i < 4; i++) {
        const int I = wv * 4 + i;
        { const int r = 4 * I + (ln >> 4); const int c = (ln & 15) ^ (r & 15);
          kbase[i] = (size_t)(b * SS + r) * HD + c * 8; }
        { const int r = 8 * I + (ln >> 3); const int c = (ln & 7) ^ (r & 7);
          vbase[i] = (size_t)r * MT + b * SS + c * 8; }
    }

    // --- prologue: issue tile 0 into buffer 0 ---
#pragma unroll
    for (int i = 0; i < 4; i++) {
        const int I = wv * 4 + i;
        __builtin_amdgcn_global_load_lds(
            (const __attribute__((address_space(1))) void*)(kg + kbase[i]),
            (__attribute__((address_space(3))) void*)&Ks[0][I * 512], 16, 0, 0);
        __builtin_amdgcn_global_load_lds(
            (const __attribute__((address_space(1))) void*)(vtg + vbase[i]),
            (__attribute__((address_space(3))) void*)&Vts[0][I * 512], 16, 0, 0);
    }

    float lrow[4] = {0.f, 0.f, 0.f, 0.f};
    f32x4 O[8];
#pragma unroll
    for (int ct = 0; ct < 8; ct++) O[ct] = 0.f;

    for (int kt = 0; kt < SS; kt += 64) {
        const int cur = (kt >> 6) & 1;
        const int nxt = cur ^ 1;

        // issue NEXT tile's loads (8 per wave), then wait only for CUR's 8
        if (kt + 64 < SS) {
#pragma unroll
            for (int i = 0; i < 4; i++) {
                const int I = wv * 4 + i;
                __builtin_amdgcn_global_load_lds(
                    (const __attribute__((address_space(1))) void*)(kg + kbase[i] + (size_t)(kt + 64) * HD),
                    (__attribute__((address_space(3))) void*)&Ks[nxt][I * 512], 16, 0, 0);
                __builtin_amdgcn_global_load_lds(
                    (const __attribute__((address_space(1))) void*)(vtg + vbase[i] + kt + 64),
                    (__attribute__((address_space(3))) void*)&Vts[nxt][I * 512], 16, 0, 0);
            }
            asm volatile("s_waitcnt vmcnt(8)" ::: "memory");
        } else {
            asm volatile("s_waitcnt vmcnt(0)" ::: "memory");
        }
        CFENCE();
        __builtin_amdgcn_s_barrier();   // CUR buffer fully staged, all waves
        CFENCE();

        // --- QK^T on buf[cur] ---
        f32x4 s[4];
#pragma unroll
        for (int ct = 0; ct < 4; ct++) s[ct] = 0.f;
        __builtin_amdgcn_s_setprio(1);
#pragma unroll
        for (int ks = 0; ks < 4; ks++) {
#pragma unroll
            for (int ct = 0; ct < 4; ct++) {
                const int n = ct * 16 + lm;
                const bf16x8 bk = *(const bf16x8*)&Ks[cur][n * 128 + (((ks << 2) | q) ^ (n & 15)) * 8];
                s[ct] = __builtin_amdgcn_mfma_f32_16x16x32_bf16(aq[ks], bk, s[ct], 0, 0, 0);
            }
        }
        __builtin_amdgcn_s_setprio(0);

        // --- p = exp(s); accumulate l; P -> LDS (bf16, swizzled, own rows) ---
#pragma unroll
        for (int ct = 0; ct < 4; ct++) {
            const int ch = ct * 2 + (lm >> 3);
#pragma unroll
            for (int r = 0; r < 4; r++) {
                const float p = __expf(s[ct][r]);
                lrow[r] += p;
                const int pr = w16 + q * 4 + r;
                Ps[pr * 64 + ((ch ^ (pr & 7)) << 3) + (lm & 7)] = (short)f2bf_fast(p);
            }
        }

        // --- PV on buf[cur] (Ps is wave-private: lgkmcnt handled by compiler) ---
        __builtin_amdgcn_s_setprio(1);
#pragma unroll
        for (int ks = 0; ks < 2; ks++) {
            const bf16x8 ap = *(const bf16x8*)&Ps[am * 64 + (((ks << 2) | q) ^ amx7) * 8];
#pragma unroll
            for (int ct = 0; ct < 8; ct++) {
                const int d = ct * 16 + lm;
                const bf16x8 bv = *(const bf16x8*)&Vts[cur][d * 64 + (((ks << 2) | q) ^ (d & 7)) * 8];
                O[ct] = __builtin_amdgcn_mfma_f32_16x16x32_bf16(ap, bv, O[ct], 0, 0, 0);
            }
        }
        __builtin_amdgcn_s_setprio(0);

        CFENCE();
        __builtin_amdgcn_s_barrier();   // all waves done reading buf[cur]
        CFENCE();
    }

    // --- epilogue: reduce l across the 16 lanes holding each row, normalize ---
#pragma unroll
    for (int msk = 1; msk < 16; msk <<= 1)
#pragma unroll
        for (int r = 0; r < 4; r++) lrow[r] += __shfl_xor(lrow[r], msk);
#pragma unroll
    for (int r = 0; r < 4; r++) {
        const float inv = 1.f / lrow[r];
        const size_t base = (size_t)(b * SS + qt * 64 + w16 + q * 4 + r) * HID + h * HD;
#pragma unroll
        for (int ct = 0; ct < 8; ct++)
            Oh[base + ct * 16 + lm] = f2bf_fast(O[ct][r] * inv);
    }
}

// ---------------------------------------------------------------------------
extern "C" void kernel_launch(void* const* d_in, const int* in_sizes, int n_in,
                              void* d_out, int out_size, void* d_ws, size_t ws_size,
                              hipStream_t stream)
{
    const float* hs = (const float*)d_in[0];
    const float* Wq = (const float*)d_in[1];
    const float* bq = (const float*)d_in[2];
    const float* Wk = (const float*)d_in[3];
    const float* bk = (const float*)d_in[4];
    const float* Wv = (const float*)d_in[5];
    const float* bv = (const float*)d_in[6];
    const float* Wo = (const float*)d_in[7];
    const float* bo = (const float*)d_in[8];
    float* out = (float*)d_out;

    // ws (bytes): hsb 16.78M | qb/Oh 16.78M | kb 1.05M | vtb 1.05M | WcT 9.44M
    char* w = (char*)d_ws;
    ushort_t* hsb  = (ushort_t*)w;  w += (size_t)MT * HID * 2;
    ushort_t* qb   = (ushort_t*)w;  w += (size_t)MT * HID * 2;   // also attn out
    ushort_t* kb   = (ushort_t*)w;  w += (size_t)MT * HD * 2;
    ushort_t* vtb  = (ushort_t*)w;  w += (size_t)HD * MT * 2;
    ushort_t* WcT  = (ushort_t*)w;  w += (size_t)NC * HID * 2;
    ushort_t* WoT  = WcT;   // reused after gemm_qkv consumed WcT (stream order)

    conv_bf16_kernel<<<(MT * HID) / (256 * 8), 256, 0, stream>>>(hs, hsb);
    // concatenated [WqT ; WkT ; WvT] rows 0..2047 | 2048..2175 | 2176..2303
    convT_kernel<<<dim3(HID / 64, HID / 64), 256, 0, stream>>>(Wq, WcT, HID, HID);
    convT_kernel<<<dim3(HID / 64, HD / 64),  256, 0, stream>>>(
        Wk, WcT + (size_t)HID * HID, HID, HD);
    convT_kernel<<<dim3(HID / 64, HD / 64),  256, 0, stream>>>(
        Wv, WcT + (size_t)(HID + HD) * HID, HID, HD);

    gemm_qkv_kernel<<<dim3(NC / 128, MT / 128), 256, 0, stream>>>(
        hsb, WcT, bq, bk, bv, qb, kb, vtb);

    convT_kernel<<<dim3(HID / 64, HID / 64), 256, 0, stream>>>(Wo, WoT, HID, HID);

    attn_mfma_kernel<<<dim3(SS / 64, NH, BB), 256, 0, stream>>>(qb, kb, vtb, qb);

    gemm_oproj_kernel<<<dim3(HID / 128, MT / 128), 256, 0, stream>>>(
        qb, WoT, bo, out, MT, HID, HID);
}

// Round 2
// 324.892 us; speedup vs baseline: 1.0376x; 1.0376x over previous
//
#include <hip/hip_runtime.h>
#include <math.h>

#define BB  2
#define SS  2048
#define HID 2048
#define NH  16
#define HD  128
#define MT  (BB * SS)      // 4096 total rows
#define NC  (HID + 2 * HD) // 2304 fused QKV output cols
#define QK_SCALE 0.08838834764831845f  // 1/sqrt(128)

typedef unsigned short ushort_t;
typedef unsigned int uint_t;
typedef __bf16 bf16x8 __attribute__((ext_vector_type(8)));
typedef short short8 __attribute__((ext_vector_type(8)));
typedef float f32x4 __attribute__((ext_vector_type(4)));

// round-to-nearest-even (used in one-time weight/activation converts)
__device__ __forceinline__ ushort_t f2bf(float x) {
    union { float f; uint_t u; } a; a.f = x;
    return (ushort_t)((a.u + 0x7FFFu + ((a.u >> 16) & 1u)) >> 16);
}
// 2-instr round-half-up — hot paths (≈RNE for continuous data)
__device__ __forceinline__ ushort_t f2bf_fast(float x) {
    union { float f; uint_t u; } a; a.f = x;
    return (ushort_t)((a.u + 0x8000u) >> 16);
}

// Swizzled LDS layout for one 128x32 bf16 tile (8 KB): logical (row r, 16B
// chunk c) -> 128B physical rows, slot ^= row'&7. All ds_read_b128 frag reads
// land 2-way per bank (free); staging computes the inverse in GLOBAL addrs.
__device__ __forceinline__ int sw_addr(int r, int c) {
    return ((r >> 1) << 6) + ((((((r & 1) << 2) | c)) ^ ((r >> 1) & 7)) << 3);
}

// compiler memory fence (no instruction) — keeps LDS/global ops from being
// hoisted/sunk across raw s_barrier (barrier builtin is not an IR fence)
#define CFENCE() asm volatile("" ::: "memory")

// ---------------------------------------------------------------------------
// fp32 -> bf16 elementwise (hs conversion), 8 elems/thread.
// ---------------------------------------------------------------------------
__global__ __launch_bounds__(256) void conv_bf16_kernel(
    const float* __restrict__ in, ushort_t* __restrict__ outb)
{
    const size_t i = ((size_t)blockIdx.x * 256 + threadIdx.x) * 8;
    const float4 a = *(const float4*)&in[i];
    const float4 b = *(const float4*)&in[i + 4];
    short8 o;
    o[0] = (short)f2bf(a.x); o[1] = (short)f2bf(a.y);
    o[2] = (short)f2bf(a.z); o[3] = (short)f2bf(a.w);
    o[4] = (short)f2bf(b.x); o[5] = (short)f2bf(b.y);
    o[6] = (short)f2bf(b.z); o[7] = (short)f2bf(b.w);
    *(short8*)&outb[i] = o;
}

// ---------------------------------------------------------------------------
// W[K][N] fp32 -> WT[N][K] bf16 (transpose), 64x64 tiles.
// ---------------------------------------------------------------------------
__global__ __launch_bounds__(256) void convT_kernel(
    const float* __restrict__ W, ushort_t* __restrict__ Th, int K, int N)
{
    __shared__ float Ts[64][65];
    const int t = threadIdx.x;
    const int k0 = blockIdx.x * 64, n0 = blockIdx.y * 64;
    const int rr = t >> 4, c4 = (t & 15) * 4;
#pragma unroll
    for (int i = 0; i < 4; i++) {
        const int k = rr + i * 16;
        const float4 v = *(const float4*)&W[(size_t)(k0 + k) * N + n0 + c4];
        Ts[k][c4 + 0] = v.x; Ts[k][c4 + 1] = v.y;
        Ts[k][c4 + 2] = v.z; Ts[k][c4 + 3] = v.w;
    }
    __syncthreads();
    const int n = t >> 2, kc = (t & 3) * 16;
    short8 hv[2];
#pragma unroll
    for (int jj = 0; jj < 16; jj++)
        hv[jj >> 3][jj & 7] = (short)f2bf(Ts[kc + jj][n]);
    const size_t ob = (size_t)(n0 + n) * K + k0 + kc;
    *(short8*)&Th[ob]     = hv[0];
    *(short8*)&Th[ob + 8] = hv[1];
}

// ---------------------------------------------------------------------------
// Fused QKV projection, plain bf16 single-product (m97 shape).
// A bf16 [M][K]; WT bf16 [NC][K]. Epilogue per 128-col tile: q/k/vT.
// ---------------------------------------------------------------------------
__global__ __launch_bounds__(256, 2) void gemm_qkv_kernel(
    const ushort_t* __restrict__ Ab, const ushort_t* __restrict__ WT,
    const float* __restrict__ bq, const float* __restrict__ bk,
    const float* __restrict__ bv,
    ushort_t* __restrict__ qb, ushort_t* __restrict__ kb,
    ushort_t* __restrict__ vtb)
{
    __shared__ short lds[8192];   // AH | BH (4096 shorts / 8 KB each)
    constexpr int AH = 0, BH = 4096;
    constexpr int K = HID;
    const int t  = threadIdx.x;
    const int wv = t >> 6, ln = t & 63;
    const int row0 = blockIdx.y * 128, col0 = blockIdx.x * 128;

    size_t agbase[2], bgbase[2];
    int    lbase[2];
#pragma unroll
    for (int i = 0; i < 2; i++) {
        const int I = wv * 2 + i;
        const int lrow = I * 8 + (ln >> 3);
        const int sb = (ln & 7) ^ (lrow & 7);
        const int rr = lrow * 2 + (sb >> 2);
        const int cc = sb & 3;
        agbase[i] = (size_t)(row0 + rr) * K + cc * 8;
        bgbase[i] = (size_t)(col0 + rr) * K + cc * 8;
        lbase[i] = I * 512;
    }

    const int wm0 = (wv & 1) * 64, wn0 = (wv >> 1) * 64;
    const int q = ln >> 4, lm = ln & 15;
    int aoff[4], boff[4];
#pragma unroll
    for (int i = 0; i < 4; i++) aoff[i] = sw_addr(wm0 + i * 16 + lm, q);
#pragma unroll
    for (int j = 0; j < 4; j++) boff[j] = sw_addr(wn0 + j * 16 + lm, q);

    f32x4 acc[4][4];
#pragma unroll
    for (int i = 0; i < 4; i++)
#pragma unroll
        for (int j = 0; j < 4; j++) acc[i][j] = 0.f;

    for (int k0 = 0; k0 < K; k0 += 32) {
        __syncthreads();
#pragma unroll
        for (int i = 0; i < 2; i++) {
            __builtin_amdgcn_global_load_lds(
                (const __attribute__((address_space(1))) void*)(Ab + agbase[i] + k0),
                (__attribute__((address_space(3))) void*)&lds[AH + lbase[i]], 16, 0, 0);
            __builtin_amdgcn_global_load_lds(
                (const __attribute__((address_space(1))) void*)(WT + bgbase[i] + k0),
                (__attribute__((address_space(3))) void*)&lds[BH + lbase[i]], 16, 0, 0);
        }
        __syncthreads();

        bf16x8 ah[4], bh[4];
#pragma unroll
        for (int i = 0; i < 4; i++) ah[i] = *(const bf16x8*)&lds[AH + aoff[i]];
#pragma unroll
        for (int j = 0; j < 4; j++) bh[j] = *(const bf16x8*)&lds[BH + boff[j]];
#pragma unroll
        for (int i = 0; i < 4; i++)
#pragma unroll
            for (int j = 0; j < 4; j++)
                acc[i][j] = __builtin_amdgcn_mfma_f32_16x16x32_bf16(ah[i], bh[j], acc[i][j], 0, 0, 0);
    }

    // epilogue: tile is entirely q (col0<2048), k (col0==2048) or v (col0==2176)
    const int mode = (col0 < HID) ? 0 : ((col0 == HID) ? 1 : 2);
    const float* bsel = (mode == 0) ? bq : ((mode == 1) ? bk : bv);
    const int noff = (mode == 0) ? 0 : ((mode == 1) ? HID : HID + HD);
    float bj[4];
#pragma unroll
    for (int j = 0; j < 4; j++) bj[j] = bsel[col0 - noff + wn0 + j * 16 + lm];
#pragma unroll
    for (int i = 0; i < 4; i++) {
        const int mb = row0 + wm0 + i * 16 + q * 4;
#pragma unroll
        for (int j = 0; j < 4; j++) {
            const int nn = col0 + wn0 + j * 16 + lm;
#pragma unroll
            for (int rr2 = 0; rr2 < 4; rr2++) {
                const float v = acc[i][j][rr2] + bj[j];
                if (mode == 0)      qb [(size_t)(mb + rr2) * HID + nn]           = f2bf_fast(v * QK_SCALE);
                else if (mode == 1) kb [(size_t)(mb + rr2) * HD + (nn - HID)]    = f2bf_fast(v);
                else                vtb[(size_t)(nn - HID - HD) * MT + mb + rr2] = f2bf_fast(v);
            }
        }
    }
}

// ---------------------------------------------------------------------------
// O-projection, plain bf16 single-product. A bf16 [M][K]; WT bf16 [N][K].
// Output fp32 + bias.
// ---------------------------------------------------------------------------
__global__ __launch_bounds__(256, 2) void gemm_oproj_kernel(
    const ushort_t* __restrict__ Ab, const ushort_t* __restrict__ WT,
    const float* __restrict__ bias, float* __restrict__ C, int M, int N, int K)
{
    __shared__ short lds[8192];
    constexpr int AH = 0, BH = 4096;
    const int t  = threadIdx.x;
    const int wv = t >> 6, ln = t & 63;
    const int row0 = blockIdx.y * 128, col0 = blockIdx.x * 128;

    size_t agbase[2], bgbase[2];
    int    lbase[2];
#pragma unroll
    for (int i = 0; i < 2; i++) {
        const int I = wv * 2 + i;
        const int lrow = I * 8 + (ln >> 3);
        const int sb = (ln & 7) ^ (lrow & 7);
        const int rr = lrow * 2 + (sb >> 2);
        const int cc = sb & 3;
        agbase[i] = (size_t)(row0 + rr) * K + cc * 8;
        bgbase[i] = (size_t)(col0 + rr) * K + cc * 8;
        lbase[i] = I * 512;
    }

    const int wm0 = (wv & 1) * 64, wn0 = (wv >> 1) * 64;
    const int q = ln >> 4, lm = ln & 15;
    int aoff[4], boff[4];
#pragma unroll
    for (int i = 0; i < 4; i++) aoff[i] = sw_addr(wm0 + i * 16 + lm, q);
#pragma unroll
    for (int j = 0; j < 4; j++) boff[j] = sw_addr(wn0 + j * 16 + lm, q);

    f32x4 acc[4][4];
#pragma unroll
    for (int i = 0; i < 4; i++)
#pragma unroll
        for (int j = 0; j < 4; j++) acc[i][j] = 0.f;

    for (int k0 = 0; k0 < K; k0 += 32) {
        __syncthreads();
#pragma unroll
        for (int i = 0; i < 2; i++) {
            __builtin_amdgcn_global_load_lds(
                (const __attribute__((address_space(1))) void*)(Ab + agbase[i] + k0),
                (__attribute__((address_space(3))) void*)&lds[AH + lbase[i]], 16, 0, 0);
            __builtin_amdgcn_global_load_lds(
                (const __attribute__((address_space(1))) void*)(WT + bgbase[i] + k0),
                (__attribute__((address_space(3))) void*)&lds[BH + lbase[i]], 16, 0, 0);
        }
        __syncthreads();

        bf16x8 ah[4], bh[4];
#pragma unroll
        for (int i = 0; i < 4; i++) ah[i] = *(const bf16x8*)&lds[AH + aoff[i]];
#pragma unroll
        for (int j = 0; j < 4; j++) bh[j] = *(const bf16x8*)&lds[BH + boff[j]];
#pragma unroll
        for (int i = 0; i < 4; i++)
#pragma unroll
            for (int j = 0; j < 4; j++)
                acc[i][j] = __builtin_amdgcn_mfma_f32_16x16x32_bf16(ah[i], bh[j], acc[i][j], 0, 0, 0);
    }

    float bj[4];
#pragma unroll
    for (int j = 0; j < 4; j++) bj[j] = bias[col0 + wn0 + j * 16 + lm];
#pragma unroll
    for (int i = 0; i < 4; i++) {
        const int mb = row0 + wm0 + i * 16 + q * 4;
#pragma unroll
        for (int j = 0; j < 4; j++) {
            const int nn = col0 + wn0 + j * 16 + lm;
#pragma unroll
            for (int rr2 = 0; rr2 < 4; rr2++)
                C[(size_t)(mb + rr2) * N + nn] = acc[i][j][rr2] + bj[j];
        }
    }
}

// ---------------------------------------------------------------------------
// MFMA flash attention (MQA), bf16/fp32, no online max (scores bounded).
// v3: SINGLE-buffer phase-split pipeline (LDS stays 40 KB -> 4 blocks/CU,
// the v2 post-mortem showed occupancy is binding). QK^T reads only Ks and
// PV reads only Vts, so:
//   barrier(QK^T reads done) -> issue K(t+1) into Ks   (lands under sm+PV)
//   barrier(PV reads done)   -> issue V(t+1) into Vts  (lands under next QK^T)
// Waits are COUNTED (vmcnt(4): own 4 younger loads in flight), never a drain
// in the main loop. Issue order is always K-block then V-block so the vmcnt
// arithmetic is exact (oldest-first retirement). T5 setprio around MFMA.
// 4 barriers/tile vs 2+full-drain.
// Output plain bf16, aliases qg block-safely (Q consumed before O written).
// ---------------------------------------------------------------------------
__global__ __launch_bounds__(256, 4) void attn_mfma_kernel(
    const ushort_t* __restrict__ qg, const ushort_t* __restrict__ kg,
    const ushort_t* __restrict__ vtg, ushort_t* Oh)
{
    __shared__ short Ks[8192], Vts[8192], Ps[4096];
    const int b = blockIdx.z, h = blockIdx.y, qt = blockIdx.x;
    const int t = threadIdx.x, wv = t >> 6, ln = t & 63;
    const int q = ln >> 4, lm = ln & 15;
    const int w16 = wv * 16;
    const int am = w16 + lm, amx = am & 15, amx7 = am & 7;

    // --- stage Q through Ks, pull A-frags to registers ---
#pragma unroll
    for (int i = 0; i < 4; i++) {
        const int I = wv * 4 + i;
        const int r = 4 * I + (ln >> 4);
        const int c = (ln & 15) ^ (r & 15);
        const ushort_t* src = qg + (size_t)(b * SS + qt * 64 + r) * HID + h * HD + c * 8;
        __builtin_amdgcn_global_load_lds((const __attribute__((address_space(1))) void*)src,
            (__attribute__((address_space(3))) void*)&Ks[I * 512], 16, 0, 0);
    }
    __syncthreads();
    bf16x8 aq[4];
#pragma unroll
    for (int ks = 0; ks < 4; ks++)
        aq[ks] = *(const bf16x8*)&Ks[am * 128 + (((ks << 2) | q) ^ amx) * 8];
    __syncthreads();   // all waves hold Q frags before tile-0 K staging

    size_t kbase[4], vbase[4];
#pragma unroll
    for (int i = 0; i < 4; i++) {
        const int I = wv * 4 + i;
        { const int r = 4 * I + (ln >> 4); const int c = (ln & 15) ^ (r & 15);
          kbase[i] = (size_t)(b * SS + r) * HD + c * 8; }
        { const int r = 8 * I + (ln >> 3); const int c = (ln & 7) ^ (r & 7);
          vbase[i] = (size_t)r * MT + b * SS + c * 8; }
    }

    // --- prologue: issue K(0) then V(0) (K-block strictly before V-block) ---
#pragma unroll
    for (int i = 0; i < 4; i++) {
        const int I = wv * 4 + i;
        __builtin_amdgcn_global_load_lds(
            (const __attribute__((address_space(1))) void*)(kg + kbase[i]),
            (__attribute__((address_space(3))) void*)&Ks[I * 512], 16, 0, 0);
    }
#pragma unroll
    for (int i = 0; i < 4; i++) {
        const int I = wv * 4 + i;
        __builtin_amdgcn_global_load_lds(
            (const __attribute__((address_space(1))) void*)(vtg + vbase[i]),
            (__attribute__((address_space(3))) void*)&Vts[I * 512], 16, 0, 0);
    }

    float lrow[4] = {0.f, 0.f, 0.f, 0.f};
    f32x4 O[8];
#pragma unroll
    for (int ct = 0; ct < 8; ct++) O[ct] = 0.f;

    for (int kt = 0; kt < SS; kt += 64) {
        const int more = (kt + 64 < SS);

        // own K(t) landed (4 younger V(t) loads still in flight)
        asm volatile("s_waitcnt vmcnt(4)" ::: "memory");
        CFENCE();
        __builtin_amdgcn_s_barrier();   // K(t) visible to all waves
        CFENCE();

        // --- QK^T (reads Ks only) ---
        f32x4 s[4];
#pragma unroll
        for (int ct = 0; ct < 4; ct++) s[ct] = 0.f;
        __builtin_amdgcn_s_setprio(1);
#pragma unroll
        for (int ks = 0; ks < 4; ks++) {
#pragma unroll
            for (int ct = 0; ct < 4; ct++) {
                const int n = ct * 16 + lm;
                const bf16x8 bk = *(const bf16x8*)&Ks[n * 128 + (((ks << 2) | q) ^ (n & 15)) * 8];
                s[ct] = __builtin_amdgcn_mfma_f32_16x16x32_bf16(aq[ks], bk, s[ct], 0, 0, 0);
            }
        }
        __builtin_amdgcn_s_setprio(0);

        CFENCE();
        __builtin_amdgcn_s_barrier();   // ALL waves done reading Ks(t)
        CFENCE();
        if (more) {                     // prefetch K(t+1) under sm+PV
#pragma unroll
            for (int i = 0; i < 4; i++) {
                const int I = wv * 4 + i;
                __builtin_amdgcn_global_load_lds(
                    (const __attribute__((address_space(1))) void*)(kg + kbase[i] + (size_t)(kt + 64) * HD),
                    (__attribute__((address_space(3))) void*)&Ks[I * 512], 16, 0, 0);
            }
        }

        // --- p = exp(s); accumulate l; P -> LDS (bf16, swizzled, own rows) ---
#pragma unroll
        for (int ct = 0; ct < 4; ct++) {
            const int ch = ct * 2 + (lm >> 3);
#pragma unroll
            for (int r = 0; r < 4; r++) {
                const float p = __expf(s[ct][r]);
                lrow[r] += p;
                const int pr = w16 + q * 4 + r;
                Ps[pr * 64 + ((ch ^ (pr & 7)) << 3) + (lm & 7)] = (short)f2bf_fast(p);
            }
        }

        // own V(t) landed (4 younger K(t+1) loads in flight, if any)
        if (more) asm volatile("s_waitcnt vmcnt(4)" ::: "memory");
        else      asm volatile("s_waitcnt vmcnt(0)" ::: "memory");
        CFENCE();
        __builtin_amdgcn_s_barrier();   // V(t) visible to all waves
        CFENCE();

        // --- PV (reads Vts + own Ps rows) ---
        __builtin_amdgcn_s_setprio(1);
#pragma unroll
        for (int ks = 0; ks < 2; ks++) {
            const bf16x8 ap = *(const bf16x8*)&Ps[am * 64 + (((ks << 2) | q) ^ amx7) * 8];
#pragma unroll
            for (int ct = 0; ct < 8; ct++) {
                const int d = ct * 16 + lm;
                const bf16x8 bv = *(const bf16x8*)&Vts[d * 64 + (((ks << 2) | q) ^ (d & 7)) * 8];
                O[ct] = __builtin_amdgcn_mfma_f32_16x16x32_bf16(ap, bv, O[ct], 0, 0, 0);
            }
        }
        __builtin_amdgcn_s_setprio(0);

        CFENCE();
        __builtin_amdgcn_s_barrier();   // ALL waves done reading Vts(t)
        CFENCE();
        if (more) {                     // prefetch V(t+1) under next QK^T
#pragma unroll
            for (int i = 0; i < 4; i++) {
                const int I = wv * 4 + i;
                __builtin_amdgcn_global_load_lds(
                    (const __attribute__((address_space(1))) void*)(vtg + vbase[i] + kt + 64),
                    (__attribute__((address_space(3))) void*)&Vts[I * 512], 16, 0, 0);
            }
        }
    }

    // --- epilogue: reduce l across the 16 lanes holding each row, normalize ---
#pragma unroll
    for (int msk = 1; msk < 16; msk <<= 1)
#pragma unroll
        for (int r = 0; r < 4; r++) lrow[r] += __shfl_xor(lrow[r], msk);
#pragma unroll
    for (int r = 0; r < 4; r++) {
        const float inv = 1.f / lrow[r];
        const size_t base = (size_t)(b * SS + qt * 64 + w16 + q * 4 + r) * HID + h * HD;
#pragma unroll
        for (int ct = 0; ct < 8; ct++)
            Oh[base + ct * 16 + lm] = f2bf_fast(O[ct][r] * inv);
    }
}

// ---------------------------------------------------------------------------
extern "C" void kernel_launch(void* const* d_in, const int* in_sizes, int n_in,
                              void* d_out, int out_size, void* d_ws, size_t ws_size,
                              hipStream_t stream)
{
    const float* hs = (const float*)d_in[0];
    const float* Wq = (const float*)d_in[1];
    const float* bq = (const float*)d_in[2];
    const float* Wk = (const float*)d_in[3];
    const float* bk = (const float*)d_in[4];
    const float* Wv = (const float*)d_in[5];
    const float* bv = (const float*)d_in[6];
    const float* Wo = (const float*)d_in[7];
    const float* bo = (const float*)d_in[8];
    float* out = (float*)d_out;

    // ws (bytes): hsb 16.78M | qb/Oh 16.78M | kb 1.05M | vtb 1.05M | WcT 9.44M
    char* w = (char*)d_ws;
    ushort_t* hsb  = (ushort_t*)w;  w += (size_t)MT * HID * 2;
    ushort_t* qb   = (ushort_t*)w;  w += (size_t)MT * HID * 2;   // also attn out
    ushort_t* kb   = (ushort_t*)w;  w += (size_t)MT * HD * 2;
    ushort_t* vtb  = (ushort_t*)w;  w += (size_t)HD * MT * 2;
    ushort_t* WcT  = (ushort_t*)w;  w += (size_t)NC * HID * 2;
    ushort_t* WoT  = WcT;   // reused after gemm_qkv consumed WcT (stream order)

    conv_bf16_kernel<<<(MT * HID) / (256 * 8), 256, 0, stream>>>(hs, hsb);
    // concatenated [WqT ; WkT ; WvT] rows 0..2047 | 2048..2175 | 2176..2303
    convT_kernel<<<dim3(HID / 64, HID / 64), 256, 0, stream>>>(Wq, WcT, HID, HID);
    convT_kernel<<<dim3(HID / 64, HD / 64),  256, 0, stream>>>(
        Wk, WcT + (size_t)HID * HID, HID, HD);
    convT_kernel<<<dim3(HID / 64, HD / 64),  256, 0, stream>>>(
        Wv, WcT + (size_t)(HID + HD) * HID, HID, HD);

    gemm_qkv_kernel<<<dim3(NC / 128, MT / 128), 256, 0, stream>>>(
        hsb, WcT, bq, bk, bv, qb, kb, vtb);

    convT_kernel<<<dim3(HID / 64, HID / 64), 256, 0, stream>>>(Wo, WoT, HID, HID);

    attn_mfma_kernel<<<dim3(SS / 64, NH, BB), 256, 0, stream>>>(qb, kb, vtb, qb);

    gemm_oproj_kernel<<<dim3(HID / 128, MT / 128), 256, 0, stream>>>(
        qb, WoT, bo, out, MT, HID, HID);
}

// Round 3
// 321.963 us; speedup vs baseline: 1.0471x; 1.0091x over previous
//
#include <hip/hip_runtime.h>
#include <math.h>

#define BB  2
#define SS  2048
#define HID 2048
#define NH  16
#define HD  128
#define MT  (BB * SS)      // 4096 total rows
#define NC  (HID + 2 * HD) // 2304 fused QKV output cols
#define QK_SCALE 0.08838834764831845f  // 1/sqrt(128)

typedef unsigned short ushort_t;
typedef unsigned int uint_t;
typedef __bf16 bf16x8 __attribute__((ext_vector_type(8)));
typedef short short8 __attribute__((ext_vector_type(8)));
typedef float f32x4 __attribute__((ext_vector_type(4)));

// round-to-nearest-even (used in one-time weight/activation converts)
__device__ __forceinline__ ushort_t f2bf(float x) {
    union { float f; uint_t u; } a; a.f = x;
    return (ushort_t)((a.u + 0x7FFFu + ((a.u >> 16) & 1u)) >> 16);
}
// 2-instr round-half-up — hot paths (≈RNE for continuous data)
__device__ __forceinline__ ushort_t f2bf_fast(float x) {
    union { float f; uint_t u; } a; a.f = x;
    return (ushort_t)((a.u + 0x8000u) >> 16);
}

// Swizzled LDS layout for one 128x32 bf16 tile (8 KB): logical (row r, 16B
// chunk c) -> 128B physical rows, slot ^= row'&7. All ds_read_b128 frag reads
// land 2-way per bank (free); staging computes the inverse in GLOBAL addrs.
__device__ __forceinline__ int sw_addr(int r, int c) {
    return ((r >> 1) << 6) + ((((((r & 1) << 2) | c)) ^ ((r >> 1) & 7)) << 3);
}

// compiler memory fence (no instruction) — keeps LDS/global ops from being
// hoisted/sunk across raw s_barrier (barrier builtin is not an IR fence)
#define CFENCE() asm volatile("" ::: "memory")

// ---------------------------------------------------------------------------
// fp32 -> bf16 elementwise (hs conversion), 8 elems/thread.
// ---------------------------------------------------------------------------
__global__ __launch_bounds__(256) void conv_bf16_kernel(
    const float* __restrict__ in, ushort_t* __restrict__ outb)
{
    const size_t i = ((size_t)blockIdx.x * 256 + threadIdx.x) * 8;
    const float4 a = *(const float4*)&in[i];
    const float4 b = *(const float4*)&in[i + 4];
    short8 o;
    o[0] = (short)f2bf(a.x); o[1] = (short)f2bf(a.y);
    o[2] = (short)f2bf(a.z); o[3] = (short)f2bf(a.w);
    o[4] = (short)f2bf(b.x); o[5] = (short)f2bf(b.y);
    o[6] = (short)f2bf(b.z); o[7] = (short)f2bf(b.w);
    *(short8*)&outb[i] = o;
}

// ---------------------------------------------------------------------------
// W[K][N] fp32 -> WT[N][K] bf16 (transpose), 64x64 tiles.
// ---------------------------------------------------------------------------
__global__ __launch_bounds__(256) void convT_kernel(
    const float* __restrict__ W, ushort_t* __restrict__ Th, int K, int N)
{
    __shared__ float Ts[64][65];
    const int t = threadIdx.x;
    const int k0 = blockIdx.x * 64, n0 = blockIdx.y * 64;
    const int rr = t >> 4, c4 = (t & 15) * 4;
#pragma unroll
    for (int i = 0; i < 4; i++) {
        const int k = rr + i * 16;
        const float4 v = *(const float4*)&W[(size_t)(k0 + k) * N + n0 + c4];
        Ts[k][c4 + 0] = v.x; Ts[k][c4 + 1] = v.y;
        Ts[k][c4 + 2] = v.z; Ts[k][c4 + 3] = v.w;
    }
    __syncthreads();
    const int n = t >> 2, kc = (t & 3) * 16;
    short8 hv[2];
#pragma unroll
    for (int jj = 0; jj < 16; jj++)
        hv[jj >> 3][jj & 7] = (short)f2bf(Ts[kc + jj][n]);
    const size_t ob = (size_t)(n0 + n) * K + k0 + kc;
    *(short8*)&Th[ob]     = hv[0];
    *(short8*)&Th[ob + 8] = hv[1];
}

// ---------------------------------------------------------------------------
// Fused QKV projection, plain bf16 single-product (m97 shape).
// A bf16 [M][K]; WT bf16 [NC][K]. Epilogue per 128-col tile: q/k/vT.
// ---------------------------------------------------------------------------
__global__ __launch_bounds__(256, 2) void gemm_qkv_kernel(
    const ushort_t* __restrict__ Ab, const ushort_t* __restrict__ WT,
    const float* __restrict__ bq, const float* __restrict__ bk,
    const float* __restrict__ bv,
    ushort_t* __restrict__ qb, ushort_t* __restrict__ kb,
    ushort_t* __restrict__ vtb)
{
    __shared__ short lds[8192];   // AH | BH (4096 shorts / 8 KB each)
    constexpr int AH = 0, BH = 4096;
    constexpr int K = HID;
    const int t  = threadIdx.x;
    const int wv = t >> 6, ln = t & 63;
    const int row0 = blockIdx.y * 128, col0 = blockIdx.x * 128;

    size_t agbase[2], bgbase[2];
    int    lbase[2];
#pragma unroll
    for (int i = 0; i < 2; i++) {
        const int I = wv * 2 + i;
        const int lrow = I * 8 + (ln >> 3);
        const int sb = (ln & 7) ^ (lrow & 7);
        const int rr = lrow * 2 + (sb >> 2);
        const int cc = sb & 3;
        agbase[i] = (size_t)(row0 + rr) * K + cc * 8;
        bgbase[i] = (size_t)(col0 + rr) * K + cc * 8;
        lbase[i] = I * 512;
    }

    const int wm0 = (wv & 1) * 64, wn0 = (wv >> 1) * 64;
    const int q = ln >> 4, lm = ln & 15;
    int aoff[4], boff[4];
#pragma unroll
    for (int i = 0; i < 4; i++) aoff[i] = sw_addr(wm0 + i * 16 + lm, q);
#pragma unroll
    for (int j = 0; j < 4; j++) boff[j] = sw_addr(wn0 + j * 16 + lm, q);

    f32x4 acc[4][4];
#pragma unroll
    for (int i = 0; i < 4; i++)
#pragma unroll
        for (int j = 0; j < 4; j++) acc[i][j] = 0.f;

    for (int k0 = 0; k0 < K; k0 += 32) {
        __syncthreads();
#pragma unroll
        for (int i = 0; i < 2; i++) {
            __builtin_amdgcn_global_load_lds(
                (const __attribute__((address_space(1))) void*)(Ab + agbase[i] + k0),
                (__attribute__((address_space(3))) void*)&lds[AH + lbase[i]], 16, 0, 0);
            __builtin_amdgcn_global_load_lds(
                (const __attribute__((address_space(1))) void*)(WT + bgbase[i] + k0),
                (__attribute__((address_space(3))) void*)&lds[BH + lbase[i]], 16, 0, 0);
        }
        __syncthreads();

        bf16x8 ah[4], bh[4];
#pragma unroll
        for (int i = 0; i < 4; i++) ah[i] = *(const bf16x8*)&lds[AH + aoff[i]];
#pragma unroll
        for (int j = 0; j < 4; j++) bh[j] = *(const bf16x8*)&lds[BH + boff[j]];
#pragma unroll
        for (int i = 0; i < 4; i++)
#pragma unroll
            for (int j = 0; j < 4; j++)
                acc[i][j] = __builtin_amdgcn_mfma_f32_16x16x32_bf16(ah[i], bh[j], acc[i][j], 0, 0, 0);
    }

    // epilogue: tile is entirely q (col0<2048), k (col0==2048) or v (col0==2176)
    const int mode = (col0 < HID) ? 0 : ((col0 == HID) ? 1 : 2);
    const float* bsel = (mode == 0) ? bq : ((mode == 1) ? bk : bv);
    const int noff = (mode == 0) ? 0 : ((mode == 1) ? HID : HID + HD);
    float bj[4];
#pragma unroll
    for (int j = 0; j < 4; j++) bj[j] = bsel[col0 - noff + wn0 + j * 16 + lm];
#pragma unroll
    for (int i = 0; i < 4; i++) {
        const int mb = row0 + wm0 + i * 16 + q * 4;
#pragma unroll
        for (int j = 0; j < 4; j++) {
            const int nn = col0 + wn0 + j * 16 + lm;
#pragma unroll
            for (int rr2 = 0; rr2 < 4; rr2++) {
                const float v = acc[i][j][rr2] + bj[j];
                if (mode == 0)      qb [(size_t)(mb + rr2) * HID + nn]           = f2bf_fast(v * QK_SCALE);
                else if (mode == 1) kb [(size_t)(mb + rr2) * HD + (nn - HID)]    = f2bf_fast(v);
                else                vtb[(size_t)(nn - HID - HD) * MT + mb + rr2] = f2bf_fast(v);
            }
        }
    }
}

// ---------------------------------------------------------------------------
// O-projection, plain bf16 single-product. A bf16 [M][K]; WT bf16 [N][K].
// Output fp32 + bias.
// ---------------------------------------------------------------------------
__global__ __launch_bounds__(256, 2) void gemm_oproj_kernel(
    const ushort_t* __restrict__ Ab, const ushort_t* __restrict__ WT,
    const float* __restrict__ bias, float* __restrict__ C, int M, int N, int K)
{
    __shared__ short lds[8192];
    constexpr int AH = 0, BH = 4096;
    const int t  = threadIdx.x;
    const int wv = t >> 6, ln = t & 63;
    const int row0 = blockIdx.y * 128, col0 = blockIdx.x * 128;

    size_t agbase[2], bgbase[2];
    int    lbase[2];
#pragma unroll
    for (int i = 0; i < 2; i++) {
        const int I = wv * 2 + i;
        const int lrow = I * 8 + (ln >> 3);
        const int sb = (ln & 7) ^ (lrow & 7);
        const int rr = lrow * 2 + (sb >> 2);
        const int cc = sb & 3;
        agbase[i] = (size_t)(row0 + rr) * K + cc * 8;
        bgbase[i] = (size_t)(col0 + rr) * K + cc * 8;
        lbase[i] = I * 512;
    }

    const int wm0 = (wv & 1) * 64, wn0 = (wv >> 1) * 64;
    const int q = ln >> 4, lm = ln & 15;
    int aoff[4], boff[4];
#pragma unroll
    for (int i = 0; i < 4; i++) aoff[i] = sw_addr(wm0 + i * 16 + lm, q);
#pragma unroll
    for (int j = 0; j < 4; j++) boff[j] = sw_addr(wn0 + j * 16 + lm, q);

    f32x4 acc[4][4];
#pragma unroll
    for (int i = 0; i < 4; i++)
#pragma unroll
        for (int j = 0; j < 4; j++) acc[i][j] = 0.f;

    for (int k0 = 0; k0 < K; k0 += 32) {
        __syncthreads();
#pragma unroll
        for (int i = 0; i < 2; i++) {
            __builtin_amdgcn_global_load_lds(
                (const __attribute__((address_space(1))) void*)(Ab + agbase[i] + k0),
                (__attribute__((address_space(3))) void*)&lds[AH + lbase[i]], 16, 0, 0);
            __builtin_amdgcn_global_load_lds(
                (const __attribute__((address_space(1))) void*)(WT + bgbase[i] + k0),
                (__attribute__((address_space(3))) void*)&lds[BH + lbase[i]], 16, 0, 0);
        }
        __syncthreads();

        bf16x8 ah[4], bh[4];
#pragma unroll
        for (int i = 0; i < 4; i++) ah[i] = *(const bf16x8*)&lds[AH + aoff[i]];
#pragma unroll
        for (int j = 0; j < 4; j++) bh[j] = *(const bf16x8*)&lds[BH + boff[j]];
#pragma unroll
        for (int i = 0; i < 4; i++)
#pragma unroll
            for (int j = 0; j < 4; j++)
                acc[i][j] = __builtin_amdgcn_mfma_f32_16x16x32_bf16(ah[i], bh[j], acc[i][j], 0, 0, 0);
    }

    float bj[4];
#pragma unroll
    for (int j = 0; j < 4; j++) bj[j] = bias[col0 + wn0 + j * 16 + lm];
#pragma unroll
    for (int i = 0; i < 4; i++) {
        const int mb = row0 + wm0 + i * 16 + q * 4;
#pragma unroll
        for (int j = 0; j < 4; j++) {
            const int nn = col0 + wn0 + j * 16 + lm;
#pragma unroll
            for (int rr2 = 0; rr2 < 4; rr2++)
                C[(size_t)(mb + rr2) * N + nn] = acc[i][j][rr2] + bj[j];
        }
    }
}

// ---------------------------------------------------------------------------
// MFMA flash attention (MQA), bf16/fp32, no online max (scores bounded).
// v4: M-REGISTER-BLOCKING — kernel is LDS-read-BW bound (17.4 MB/CU at 85-112
// B/cyc ~ 65-85 us of the 104 us). Each wave's K/V tile read volume is
// independent of its Q-row count, so each wave now owns 32 Q-rows (2 strips):
// one bk/bv ds_read_b128 feeds TWO MFMAs from registers -> LDS traffic/CU
// halves (9.2 MB). Blocks: 2 waves x 32 rows = 64 Q-rows, 128 threads.
// LDS stays 40 KB -> 4 blocks/CU (8 waves/CU, 2/SIMD - fine, BW-bound).
// Keeps v3 phase-split counted-vmcnt pipeline (8 loads/wave -> vmcnt(8))
// and T5 setprio. Output aliases qg block-safely.
// ---------------------------------------------------------------------------
__global__ __launch_bounds__(128, 2) void attn_mfma_kernel(
    const ushort_t* __restrict__ qg, const ushort_t* __restrict__ kg,
    const ushort_t* __restrict__ vtg, ushort_t* Oh)
{
    __shared__ short Ks[8192], Vts[8192], Ps[4096];
    const int b = blockIdx.z, h = blockIdx.y, qt = blockIdx.x;
    const int t = threadIdx.x, wv = t >> 6, ln = t & 63;
    const int q = ln >> 4, lm = ln & 15;
    const int w32 = wv * 32;
    const int lm7 = ln & 7;

    // --- stage Q through Ks (8 segments/wave), pull 2 strips of A-frags ---
    const ushort_t* qgb = qg + (size_t)(b * SS + qt * 64) * HID + h * HD;
#pragma unroll
    for (int i = 0; i < 8; i++) {
        const int I = wv * 8 + i;
        const int r = 4 * I + (ln >> 4);
        const int c = (ln & 15) ^ (r & 15);
        __builtin_amdgcn_global_load_lds(
            (const __attribute__((address_space(1))) void*)(qgb + (size_t)r * HID + c * 8),
            (__attribute__((address_space(3))) void*)&Ks[I * 512], 16, 0, 0);
    }
    __syncthreads();
    bf16x8 aq[2][4];
#pragma unroll
    for (int st = 0; st < 2; st++) {
        const int am = w32 + st * 16 + lm;
#pragma unroll
        for (int ks = 0; ks < 4; ks++)
            aq[st][ks] = *(const bf16x8*)&Ks[am * 128 + (((ks << 2) | q) ^ (am & 15)) * 8];
    }
    __syncthreads();   // all waves hold Q frags before tile-0 K staging

    // staging offsets (32-bit, from per-batch bases — keeps VGPR pressure down)
    const ushort_t* kgb = kg + (size_t)b * SS * HD;
    const ushort_t* vgb = vtg + b * SS;
    uint_t koff[8], voff[8];
#pragma unroll
    for (int i = 0; i < 8; i++) {
        const int I = wv * 8 + i;
        { const int r = 4 * I + (ln >> 4); const int c = (ln & 15) ^ (r & 15);
          koff[i] = (uint_t)(r * HD + c * 8); }
        { const int r = 8 * I + (ln >> 3); const int c = (ln & 7) ^ (r & 7);
          voff[i] = (uint_t)(r * MT + c * 8); }
    }

    // --- prologue: issue K(0) then V(0) (K-block strictly before V-block) ---
#pragma unroll
    for (int i = 0; i < 8; i++) {
        const int I = wv * 8 + i;
        __builtin_amdgcn_global_load_lds(
            (const __attribute__((address_space(1))) void*)(kgb + koff[i]),
            (__attribute__((address_space(3))) void*)&Ks[I * 512], 16, 0, 0);
    }
#pragma unroll
    for (int i = 0; i < 8; i++) {
        const int I = wv * 8 + i;
        __builtin_amdgcn_global_load_lds(
            (const __attribute__((address_space(1))) void*)(vgb + voff[i]),
            (__attribute__((address_space(3))) void*)&Vts[I * 512], 16, 0, 0);
    }

    float lrow[2][4] = {{0.f, 0.f, 0.f, 0.f}, {0.f, 0.f, 0.f, 0.f}};
    f32x4 O[2][8];
#pragma unroll
    for (int st = 0; st < 2; st++)
#pragma unroll
        for (int ct = 0; ct < 8; ct++) O[st][ct] = 0.f;

    for (int kt = 0; kt < SS; kt += 64) {
        const int more = (kt + 64 < SS);

        // own K(t) landed (8 younger V(t) loads still in flight)
        asm volatile("s_waitcnt vmcnt(8)" ::: "memory");
        CFENCE();
        __builtin_amdgcn_s_barrier();   // K(t) visible to all waves
        CFENCE();

        // --- QK^T (reads Ks only; each bk feeds both strips) ---
        f32x4 s[2][4];
#pragma unroll
        for (int st = 0; st < 2; st++)
#pragma unroll
            for (int ct = 0; ct < 4; ct++) s[st][ct] = 0.f;
        __builtin_amdgcn_s_setprio(1);
#pragma unroll
        for (int ks = 0; ks < 4; ks++) {
#pragma unroll
            for (int ct = 0; ct < 4; ct++) {
                const int n = ct * 16 + lm;
                const bf16x8 bk = *(const bf16x8*)&Ks[n * 128 + (((ks << 2) | q) ^ (n & 15)) * 8];
                s[0][ct] = __builtin_amdgcn_mfma_f32_16x16x32_bf16(aq[0][ks], bk, s[0][ct], 0, 0, 0);
                s[1][ct] = __builtin_amdgcn_mfma_f32_16x16x32_bf16(aq[1][ks], bk, s[1][ct], 0, 0, 0);
            }
        }
        __builtin_amdgcn_s_setprio(0);

        CFENCE();
        __builtin_amdgcn_s_barrier();   // ALL waves done reading Ks(t)
        CFENCE();
        if (more) {                     // prefetch K(t+1) under sm+PV
#pragma unroll
            for (int i = 0; i < 8; i++) {
                const int I = wv * 8 + i;
                __builtin_amdgcn_global_load_lds(
                    (const __attribute__((address_space(1))) void*)(kgb + koff[i] + (kt + 64) * HD),
                    (__attribute__((address_space(3))) void*)&Ks[I * 512], 16, 0, 0);
            }
        }

        // --- p = exp(s); accumulate l; P -> LDS (bf16, swizzled, own rows) ---
#pragma unroll
        for (int st = 0; st < 2; st++)
#pragma unroll
        for (int ct = 0; ct < 4; ct++) {
            const int ch = ct * 2 + (lm >> 3);
#pragma unroll
            for (int r = 0; r < 4; r++) {
                const float p = __expf(s[st][ct][r]);
                lrow[st][r] += p;
                const int pr = w32 + st * 16 + q * 4 + r;
                Ps[pr * 64 + ((ch ^ (pr & 7)) << 3) + lm7] = (short)f2bf_fast(p);
            }
        }

        // own V(t) landed (8 younger K(t+1) loads in flight, if any)
        if (more) asm volatile("s_waitcnt vmcnt(8)" ::: "memory");
        else      asm volatile("s_waitcnt vmcnt(0)" ::: "memory");
        CFENCE();
        __builtin_amdgcn_s_barrier();   // V(t) visible to all waves
        CFENCE();

        // --- PV (reads Vts + own Ps rows; each bv feeds both strips) ---
        __builtin_amdgcn_s_setprio(1);
#pragma unroll
        for (int ks = 0; ks < 2; ks++) {
            const bf16x8 ap0 = *(const bf16x8*)&Ps[(w32 + lm) * 64 + (((ks << 2) | q) ^ lm7) * 8];
            const bf16x8 ap1 = *(const bf16x8*)&Ps[(w32 + 16 + lm) * 64 + (((ks << 2) | q) ^ lm7) * 8];
#pragma unroll
            for (int ct = 0; ct < 8; ct++) {
                const int d = ct * 16 + lm;
                const bf16x8 bv = *(const bf16x8*)&Vts[d * 64 + (((ks << 2) | q) ^ (d & 7)) * 8];
                O[0][ct] = __builtin_amdgcn_mfma_f32_16x16x32_bf16(ap0, bv, O[0][ct], 0, 0, 0);
                O[1][ct] = __builtin_amdgcn_mfma_f32_16x16x32_bf16(ap1, bv, O[1][ct], 0, 0, 0);
            }
        }
        __builtin_amdgcn_s_setprio(0);

        CFENCE();
        __builtin_amdgcn_s_barrier();   // all waves done reading Vts(t)
        CFENCE();
        if (more) {                     // prefetch V(t+1) under next QK^T
#pragma unroll
            for (int i = 0; i < 8; i++) {
                const int I = wv * 8 + i;
                __builtin_amdgcn_global_load_lds(
                    (const __attribute__((address_space(1))) void*)(vgb + voff[i] + (kt + 64)),
                    (__attribute__((address_space(3))) void*)&Vts[I * 512], 16, 0, 0);
            }
        }
    }

    // --- epilogue: reduce l across the 16 lanes holding each row, normalize ---
#pragma unroll
    for (int msk = 1; msk < 16; msk <<= 1)
#pragma unroll
        for (int st = 0; st < 2; st++)
#pragma unroll
            for (int r = 0; r < 4; r++) lrow[st][r] += __shfl_xor(lrow[st][r], msk);
#pragma unroll
    for (int st = 0; st < 2; st++)
#pragma unroll
    for (int r = 0; r < 4; r++) {
        const float inv = 1.f / lrow[st][r];
        const size_t base = (size_t)(b * SS + qt * 64 + w32 + st * 16 + q * 4 + r) * HID + h * HD;
#pragma unroll
        for (int ct = 0; ct < 8; ct++)
            Oh[base + ct * 16 + lm] = f2bf_fast(O[st][ct][r] * inv);
    }
}

// ---------------------------------------------------------------------------
extern "C" void kernel_launch(void* const* d_in, const int* in_sizes, int n_in,
                              void* d_out, int out_size, void* d_ws, size_t ws_size,
                              hipStream_t stream)
{
    const float* hs = (const float*)d_in[0];
    const float* Wq = (const float*)d_in[1];
    const float* bq = (const float*)d_in[2];
    const float* Wk = (const float*)d_in[3];
    const float* bk = (const float*)d_in[4];
    const float* Wv = (const float*)d_in[5];
    const float* bv = (const float*)d_in[6];
    const float* Wo = (const float*)d_in[7];
    const float* bo = (const float*)d_in[8];
    float* out = (float*)d_out;

    // ws (bytes): hsb 16.78M | qb/Oh 16.78M | kb 1.05M | vtb 1.05M | WcT 9.44M
    char* w = (char*)d_ws;
    ushort_t* hsb  = (ushort_t*)w;  w += (size_t)MT * HID * 2;
    ushort_t* qb   = (ushort_t*)w;  w += (size_t)MT * HID * 2;   // also attn out
    ushort_t* kb   = (ushort_t*)w;  w += (size_t)MT * HD * 2;
    ushort_t* vtb  = (ushort_t*)w;  w += (size_t)HD * MT * 2;
    ushort_t* WcT  = (ushort_t*)w;  w += (size_t)NC * HID * 2;
    ushort_t* WoT  = WcT;   // reused after gemm_qkv consumed WcT (stream order)

    conv_bf16_kernel<<<(MT * HID) / (256 * 8), 256, 0, stream>>>(hs, hsb);
    // concatenated [WqT ; WkT ; WvT] rows 0..2047 | 2048..2175 | 2176..2303
    convT_kernel<<<dim3(HID / 64, HID / 64), 256, 0, stream>>>(Wq, WcT, HID, HID);
    convT_kernel<<<dim3(HID / 64, HD / 64),  256, 0, stream>>>(
        Wk, WcT + (size_t)HID * HID, HID, HD);
    convT_kernel<<<dim3(HID / 64, HD / 64),  256, 0, stream>>>(
        Wv, WcT + (size_t)(HID + HD) * HID, HID, HD);

    gemm_qkv_kernel<<<dim3(NC / 128, MT / 128), 256, 0, stream>>>(
        hsb, WcT, bq, bk, bv, qb, kb, vtb);

    convT_kernel<<<dim3(HID / 64, HID / 64), 256, 0, stream>>>(Wo, WoT, HID, HID);

    attn_mfma_kernel<<<dim3(SS / 64, NH, BB), 128, 0, stream>>>(qb, kb, vtb, qb);

    gemm_oproj_kernel<<<dim3(HID / 128, MT / 128), 256, 0, stream>>>(
        qb, WoT, bo, out, MT, HID, HID);
}